// Round 3
// baseline (147.789 us; speedup 1.0000x reference)
//
#include <hip/hip_runtime.h>
#include <hip/hip_bf16.h>
#include <cstdint>
#include <cstddef>

// Problem dims
#define Bb 2
#define Tt 2048
#define Dd 1024
#define Hh 16
#define DHh 64

using short8 = __attribute__((ext_vector_type(8))) short;   // 8 bf16 (4 VGPRs) MFMA operand
using f32x4  = __attribute__((ext_vector_type(4))) float;   // MFMA accumulator 16x16
using f32x16 = __attribute__((ext_vector_type(16))) float;  // MFMA accumulator 32x32
typedef unsigned short u16;

// f32 -> bf16 (RNE) scalar
__device__ __forceinline__ u16 f2bf(float f) {
    unsigned int u = __float_as_uint(f);
    u += 0x7fffu + ((u >> 16) & 1u);
    return (u16)(u >> 16);
}

// pack two f32 -> bf16x2 (v_cvt_pk_bf16_f32 via HIP API)
__device__ __forceinline__ unsigned int pk2bf(float a, float b) {
    union { __hip_bfloat162 h; unsigned int u; } c;
    c.h = __float22bfloat162_rn(float2{a, b});
    return c.u;
}

// async global->LDS, 16B per lane; LDS dest is wave-uniform base + lane*16
__device__ __forceinline__ void gload16(const void* g, void* l) {
    __builtin_amdgcn_global_load_lds((const __attribute__((address_space(1))) void*)g,
                                     (__attribute__((address_space(3))) void*)l, 16, 0, 0);
}

// ---------------------------------------------------------------------------
// Shared GEMM core: C[128x128] tile of A[M,K] @ BT[N,K]^T, bf16 in, f32 acc.
// ---------------------------------------------------------------------------
__device__ __forceinline__ void gemm_bt_core(const u16* __restrict__ A, const u16* __restrict__ BT,
                                             int K, int m0, int n0,
                                             u16* As, u16* Bs, f32x4 acc[4][4]) {
    const int tid = threadIdx.x;
    const int w = tid >> 6, lane = tid & 63;
    const int lr = lane & 15, lg = lane >> 4;
    const int wr = w >> 1, wc = w & 1;
    const int arow = lane >> 2;          // 0..15 within 16-row staging group
    const int acol = (lane & 3) * 8;     // k-chunk offset (elems)
    for (int kk = 0; kk < K; kk += 32) {
        __syncthreads();   // previous tile's reads complete before overwrite
#pragma unroll
        for (int j = 0; j < 2; ++j) {
            int r0 = w * 32 + j * 16;
            gload16(A  + (size_t)(m0 + r0 + arow) * K + kk + acol, (char*)As + r0 * 64);
            gload16(BT + (size_t)(n0 + r0 + arow) * K + kk + acol, (char*)Bs + r0 * 64);
        }
        __syncthreads();   // staging visible (drains vmcnt)
        short8 af[4], bfv[4];
#pragma unroll
        for (int m = 0; m < 4; ++m)
            af[m] = *(const short8*)((const char*)As + ((wr * 64 + m * 16 + lr) * 64 + lg * 16));
#pragma unroll
        for (int n = 0; n < 4; ++n)
            bfv[n] = *(const short8*)((const char*)Bs + ((wc * 64 + n * 16 + lr) * 64 + lg * 16));
#pragma unroll
        for (int m = 0; m < 4; ++m)
#pragma unroll
            for (int n = 0; n < 4; ++n)
                acc[m][n] = __builtin_amdgcn_mfma_f32_16x16x32_bf16(af[m], bfv[n], acc[m][n], 0, 0, 0);
    }
}

// ---------------------------------------------------------------------------
// Prep: x (f32) -> bf16
// ---------------------------------------------------------------------------
__global__ __launch_bounds__(256) void convert_x_k(const float4* __restrict__ x4,
                                                   ushort4* __restrict__ xb4, int n4) {
    int i = blockIdx.x * 256 + threadIdx.x;
    if (i >= n4) return;
    float4 v = x4[i];
    ushort4 o;
    o.x = f2bf(v.x); o.y = f2bf(v.y); o.z = f2bf(v.z); o.w = f2bf(v.w);
    xb4[i] = o;
}

// Prep: W[k][n] f32 -> WT[n][k] bf16, 4 matrices (z: Wq,Wk,Wv,Wp)
__global__ void transpose_w_k(const float* __restrict__ Wq, const float* __restrict__ Wk,
                              const float* __restrict__ Wv, const float* __restrict__ Wp,
                              u16* __restrict__ wt) {
    __shared__ float tile[32][33];
    const int z = blockIdx.z;
    const float* W = (z == 0) ? Wq : (z == 1) ? Wk : (z == 2) ? Wv : Wp;
    const int n0 = blockIdx.x * 32, k0 = blockIdx.y * 32;
    const int tx = threadIdx.x, ty = threadIdx.y;   // (32, 8)
#pragma unroll
    for (int j = 0; j < 4; ++j)
        tile[ty + j * 8][tx] = W[(size_t)(k0 + ty + j * 8) * Dd + n0 + tx];
    __syncthreads();
    u16* outp = wt + (size_t)z * Dd * Dd;
#pragma unroll
    for (int j = 0; j < 4; ++j)
        outp[(size_t)(n0 + ty + j * 8) * Dd + k0 + tx] = f2bf(tile[tx][ty + j * 8]);
}

// ---------------------------------------------------------------------------
// QKV GEMM: [4096,1024] @ [1024,3072] -> Q (scaled incl log2e, per-head),
// K (per-head), V transposed per-head [bh][dh][t].
// ---------------------------------------------------------------------------
__global__ __launch_bounds__(256) void qkv_gemm_k(const u16* __restrict__ xb, const u16* __restrict__ wt,
        const float* __restrict__ bq, const float* __restrict__ bk, const float* __restrict__ bv,
        u16* __restrict__ Qg, u16* __restrict__ Kg, u16* __restrict__ VTg) {
    __shared__ alignas(16) u16 As[128 * 32];
    __shared__ alignas(16) u16 Bs[128 * 32];
    f32x4 acc[4][4];
    const f32x4 vzero = {0.f, 0.f, 0.f, 0.f};
#pragma unroll
    for (int m = 0; m < 4; ++m)
#pragma unroll
        for (int n = 0; n < 4; ++n) acc[m][n] = vzero;
    const int m0 = blockIdx.y * 128, n0 = blockIdx.x * 128;
    gemm_bt_core(xb, wt, 1024, m0, n0, As, Bs, acc);
    const int tid = threadIdx.x, w = tid >> 6, lane = tid & 63, lr = lane & 15, lg = lane >> 4;
    const int wr = w >> 1, wc = w & 1;
    const int sec = n0 >> 10;             // 0:Q 1:K 2:V (128-tiles never straddle)
    const float* bias = (sec == 0) ? bq : (sec == 1) ? bk : bv;
    u16* dst = (sec == 0) ? Qg : (sec == 1) ? Kg : VTg;
    // Q scale: DH^-0.5 * log2(e)  -> softmax runs in exp2 domain
    const float qscale = (sec == 0) ? 0.125f * 1.4426950408889634f : 1.0f;
#pragma unroll
    for (int n = 0; n < 4; ++n) {
        int gn = n0 + wc * 64 + n * 16 + lr;
        int j = gn & 1023;
        float bj = bias[j];
        int h = j >> 6, dh = j & 63;
#pragma unroll
        for (int m = 0; m < 4; ++m) {
            int gmb = m0 + wr * 64 + m * 16 + 4 * lg;
#pragma unroll
            for (int i = 0; i < 4; ++i) {
                int gm = gmb + i;
                int b = gm >> 11, t = gm & 2047;
                float v = (acc[m][n][i] + bj) * qscale;
                size_t off;
                if (sec < 2) off = (((size_t)(b * Hh + h)) * Tt + t) * DHh + dh;       // [bh][t][dh]
                else         off = (((size_t)(b * Hh + h)) * DHh + dh) * Tt + t;       // [bh][dh][t]
                dst[off] = f2bf(v);
            }
        }
    }
}

// ---------------------------------------------------------------------------
// Flash attention, 32x32x16 MFMA, swapped operands, in-register P.
// Block = 4 waves x 32 q-rows = 128 q-rows. KV-tile = 64, double-buffered LDS.
//   S^T = mfma(Kfrag, Qfrag): lane q = lane&31; key(reg r, hi) = (r&3)+8*(r>>2)+4*hi
//   O^T = mfma(Vfrag, Pfrag): lane q = lane&31; dh same formula
// P converted to bf16 in-register (cvt_pk) and redistributed across the two
// half-waves via shfl_xor(32) to form the PV B-operand (no P LDS).
// Staging: issue next tile's global_load_lds BEFORE compute; one barrier/tile.
// ---------------------------------------------------------------------------
__global__ __launch_bounds__(256, 2) void attn_k(const u16* __restrict__ Qg, const u16* __restrict__ Kg,
        const u16* __restrict__ VTg, const int* __restrict__ dmask, u16* __restrict__ Og) {
    __shared__ alignas(16) u16 Ks[2][64 * 64];   // [buf][key][dh] rows 128B, swz 16B chunks
    __shared__ alignas(16) u16 Vs[2][64 * 64];   // [buf][dh][key] rows 128B, swz 16B chunks
    const int bh = blockIdx.x;
    const int qb = 15 - (int)blockIdx.y;         // heavy (high-q) blocks dispatched first
    const int b = bh >> 4, h = bh & 15;
    const int tid = threadIdx.x, w = tid >> 6, lane = tid & 63;
    const int lq = lane & 31, hi = lane >> 5;
    const int q0w = qb * 128 + w * 32;
    const int qrow = q0w + lq;
    // Q fragments: B-operand, k = 16*ks + 8*hi + j
    short8 qf[4];
    {
        const u16* Qbase = Qg + ((size_t)bh * Tt + qrow) * DHh;
#pragma unroll
        for (int ks = 0; ks < 4; ++ks) qf[ks] = *(const short8*)(Qbase + ks * 16 + hi * 8);
    }
    f32x16 ot0, ot1;
#pragma unroll
    for (int i = 0; i < 16; ++i) { ot0[i] = 0.f; ot1[i] = 0.f; }
    float mrow = -1e30f, lrow = 0.f;
    const int rr = lane >> 3, cc = lane & 7;     // staging row-in-group / chunk

#define STAGE(BUF, KB) do { \
    _Pragma("unroll") \
    for (int j = 0; j < 2; ++j) { \
        int r0 = w * 16 + j * 8; \
        gload16(Kg  + ((size_t)bh * Tt  + (KB) + r0 + rr) * DHh + ((cc ^ rr) * 8), (char*)&Ks[BUF][0] + r0 * 128); \
        gload16(VTg + ((size_t)bh * DHh + r0 + rr) * Tt + (KB) + ((cc ^ rr) * 8), (char*)&Vs[BUF][0] + r0 * 128); \
    } } while (0)

    const int nkt = 2 * qb + 2;
    int buf = 0;
    STAGE(0, 0);
    __syncthreads();
    for (int kt = 0; kt < nkt; ++kt) {
        const int kb = kt * 64;
        if (kt + 1 < nkt) {                      // issue next tile early (hidden under compute)
            if (buf) STAGE(0, kb + 64); else STAGE(1, kb + 64);
        }
        if (kb <= q0w + 31) {                    // wave has valid keys in this tile
            const char* KsB = (const char*)&Ks[buf][0];
            const char* VsB = (const char*)&Vs[buf][0];
            const int swz = lq & 7;
            // S^T = K Q^T
            f32x16 st0, st1;
#pragma unroll
            for (int i = 0; i < 16; ++i) { st0[i] = 0.f; st1[i] = 0.f; }
#pragma unroll
            for (int ks = 0; ks < 4; ++ks) {
                short8 kf0 = *(const short8*)(KsB + lq * 128        + (((2 * ks + hi) ^ swz) << 4));
                short8 kf1 = *(const short8*)(KsB + (32 + lq) * 128 + (((2 * ks + hi) ^ swz) << 4));
                st0 = __builtin_amdgcn_mfma_f32_32x32x16_bf16(kf0, qf[ks], st0, 0, 0, 0);
                st1 = __builtin_amdgcn_mfma_f32_32x32x16_bf16(kf1, qf[ks], st1, 0, 0, 0);
            }
            // data mask as float 0/1; causal only on this wave's single diagonal tile
            float4 km[8];
            {
                const int4* dmv = (const int4*)(dmask + (size_t)b * Tt + kb);
#pragma unroll
                for (int t = 0; t < 2; ++t)
#pragma unroll
                    for (int g = 0; g < 4; ++g) {
                        int4 mi = dmv[t * 8 + g * 2 + hi];
                        km[t * 4 + g] = make_float4((float)mi.x, (float)mi.y, (float)mi.z, (float)mi.w);
                    }
            }
            if (kb + 63 > q0w) {
#pragma unroll
                for (int t = 0; t < 2; ++t)
#pragma unroll
                    for (int g = 0; g < 4; ++g) {
                        int k4 = kb + 32 * t + 8 * g + 4 * hi;
                        float4& m4 = km[t * 4 + g];
                        if (k4 + 0 > qrow) m4.x = 0.f;
                        if (k4 + 1 > qrow) m4.y = 0.f;
                        if (k4 + 2 > qrow) m4.z = 0.f;
                        if (k4 + 3 > qrow) m4.w = 0.f;
                    }
            }
            // row max over raw scores (shift-invariant; masked entries only shrink p uniformly)
            float rm = st0[0];
#pragma unroll
            for (int i = 1; i < 16; ++i) rm = fmaxf(rm, st0[i]);
#pragma unroll
            for (int i = 0; i < 16; ++i) rm = fmaxf(rm, st1[i]);
            rm = fmaxf(rm, __shfl_xor(rm, 32));
            float mn = fmaxf(mrow, rm);
            float sc = exp2f(mrow - mn);
            mrow = mn;
            lrow *= sc;
#pragma unroll
            for (int i = 0; i < 16; ++i) { ot0[i] *= sc; ot1[i] *= sc; }
            // P = exp2(S - mn) * mask; build PV B-operand per 16-key step
            float rs = 0.f;
#pragma unroll
            for (int s = 0; s < 4; ++s) {
                float p[8];
#pragma unroll
                for (int e = 0; e < 8; ++e) {
                    float sv = (s < 2) ? ((s & 1) ? st0[8 + e] : st0[e])
                                       : ((s & 1) ? st1[8 + e] : st1[e]);
                    float mv;
                    {
                        const float4& m4 = km[(s >> 1) * 4 + (s & 1) * 2 + (e >> 2)];
                        int e3 = e & 3;
                        mv = (e3 == 0) ? m4.x : (e3 == 1) ? m4.y : (e3 == 2) ? m4.z : m4.w;
                    }
                    p[e] = exp2f(sv - mn) * mv;
                    rs += p[e];
                }
                unsigned a0 = pk2bf(p[0], p[1]), a1 = pk2bf(p[2], p[3]);
                unsigned b0 = pk2bf(p[4], p[5]), b1 = pk2bf(p[6], p[7]);
                unsigned sa0 = __shfl_xor(a0, 32), sa1 = __shfl_xor(a1, 32);
                unsigned sb0 = __shfl_xor(b0, 32), sb1 = __shfl_xor(b1, 32);
                union { uint4 u; short8 sv; } pf;
                pf.u.x = hi ? sb0 : a0;
                pf.u.y = hi ? sb1 : a1;
                pf.u.z = hi ? b0 : sa0;
                pf.u.w = hi ? b1 : sa1;
                short8 vf0 = *(const short8*)(VsB + lq * 128        + (((2 * s + hi) ^ swz) << 4));
                short8 vf1 = *(const short8*)(VsB + (32 + lq) * 128 + (((2 * s + hi) ^ swz) << 4));
                ot0 = __builtin_amdgcn_mfma_f32_32x32x16_bf16(vf0, pf.sv, ot0, 0, 0, 0);
                ot1 = __builtin_amdgcn_mfma_f32_32x32x16_bf16(vf1, pf.sv, ot1, 0, 0, 0);
            }
            rs += __shfl_xor(rs, 32);
            lrow += rs;
        }
        __syncthreads();   // drains vmcnt (next tile staged) + lgkm (my reads done)
        buf ^= 1;
    }
#undef STAGE
    // epilogue: normalize, write O[qrow][h*64 + dh], dh = 32d + 8g + 4hi + e
    float inv = lrow > 0.f ? 1.0f / lrow : 0.f;
    u16* ob = Og + ((size_t)(b * Tt + qrow)) * Dd + h * DHh;
#pragma unroll
    for (int d = 0; d < 2; ++d) {
#pragma unroll
        for (int g = 0; g < 4; ++g) {
            uint2 pw;
            float v0 = (d ? ot1[4 * g + 0] : ot0[4 * g + 0]) * inv;
            float v1 = (d ? ot1[4 * g + 1] : ot0[4 * g + 1]) * inv;
            float v2 = (d ? ot1[4 * g + 2] : ot0[4 * g + 2]) * inv;
            float v3 = (d ? ot1[4 * g + 3] : ot0[4 * g + 3]) * inv;
            pw.x = pk2bf(v0, v1);
            pw.y = pk2bf(v2, v3);
            *(uint2*)(ob + d * 32 + g * 8 + hi * 4) = pw;
        }
    }
}

// ---------------------------------------------------------------------------
// Output GEMM: O[4096,1024] @ Wp -> f32 out, + bp, * data_mask
// ---------------------------------------------------------------------------
__global__ __launch_bounds__(256) void out_gemm_k(const u16* __restrict__ Og, const u16* __restrict__ wpt,
        const float* __restrict__ bp, const int* __restrict__ dmask, float* __restrict__ out) {
    __shared__ alignas(16) u16 As[128 * 32];
    __shared__ alignas(16) u16 Bs[128 * 32];
    f32x4 acc[4][4];
    const f32x4 vzero = {0.f, 0.f, 0.f, 0.f};
#pragma unroll
    for (int m = 0; m < 4; ++m)
#pragma unroll
        for (int n = 0; n < 4; ++n) acc[m][n] = vzero;
    const int m0 = blockIdx.y * 128, n0 = blockIdx.x * 128;
    gemm_bt_core(Og, wpt, 1024, m0, n0, As, Bs, acc);
    const int tid = threadIdx.x, w = tid >> 6, lane = tid & 63, lr = lane & 15, lg = lane >> 4;
    const int wr = w >> 1, wc = w & 1;
#pragma unroll
    for (int n = 0; n < 4; ++n) {
        int gn = n0 + wc * 64 + n * 16 + lr;
        float bj = bp[gn];
#pragma unroll
        for (int m = 0; m < 4; ++m) {
            int gmb = m0 + wr * 64 + m * 16 + 4 * lg;
#pragma unroll
            for (int i = 0; i < 4; ++i) {
                int gm = gmb + i;
                float dmv = (float)dmask[gm];
                out[(size_t)gm * Dd + gn] = (acc[m][n][i] + bj) * dmv;
            }
        }
    }
}

// ---------------------------------------------------------------------------
// Workspace layout (bytes):
//   [0,8M)    xb  bf16 [4096][1024]   (reused as Og after qkv_gemm)
//   [8M,16M)  wt  bf16 [4][1024][1024] (WqT,WkT,WvT,WpT)
//   [16M,24M) Qg  bf16 [32][2048][64]  (scaled incl log2e)
//   [24M,32M) Kg  bf16 [32][2048][64]
//   [32M,40M) VTg bf16 [32][64][2048]
// ---------------------------------------------------------------------------
extern "C" void kernel_launch(void* const* d_in, const int* in_sizes, int n_in,
                              void* d_out, int out_size, void* d_ws, size_t ws_size,
                              hipStream_t stream) {
    const float* x   = (const float*)d_in[0];
    const int*  dmask = (const int*)d_in[1];
    const float* Wq = (const float*)d_in[2];
    const float* bq = (const float*)d_in[3];
    const float* Wk = (const float*)d_in[4];
    const float* bk = (const float*)d_in[5];
    const float* Wv = (const float*)d_in[6];
    const float* bv = (const float*)d_in[7];
    const float* Wp = (const float*)d_in[8];
    const float* bp = (const float*)d_in[9];
    float* out = (float*)d_out;
    char* ws = (char*)d_ws;
    u16* xb  = (u16*)(ws);
    u16* wt  = (u16*)(ws + ((size_t)8 << 20));
    u16* Qg  = (u16*)(ws + ((size_t)16 << 20));
    u16* Kg  = (u16*)(ws + ((size_t)24 << 20));
    u16* VTg = (u16*)(ws + ((size_t)32 << 20));
    u16* Og  = xb;   // reuse: xb consumed by qkv_gemm before attn writes Og

    convert_x_k<<<dim3(4096), dim3(256), 0, stream>>>((const float4*)x, (ushort4*)xb, (Bb * Tt * Dd) / 4);
    transpose_w_k<<<dim3(32, 32, 4), dim3(32, 8), 0, stream>>>(Wq, Wk, Wv, Wp, wt);
    qkv_gemm_k<<<dim3(24, 32), dim3(256), 0, stream>>>(xb, wt, bq, bk, bv, Qg, Kg, VTg);
    attn_k<<<dim3(32, 16), dim3(256), 0, stream>>>(Qg, Kg, VTg, dmask, Og);
    out_gemm_k<<<dim3(8, 32), dim3(256), 0, stream>>>(Og, wt + (size_t)3 * Dd * Dd, bp, dmask, out);
}